// Round 3
// baseline (206.118 us; speedup 1.0000x reference)
//
#include <hip/hip_runtime.h>
#include <hip/hip_bf16.h>
#include <math.h>

typedef __bf16 bf16x8 __attribute__((ext_vector_type(8)));
typedef unsigned short u16x8 __attribute__((ext_vector_type(8)));
typedef unsigned short u16x4 __attribute__((ext_vector_type(4)));
typedef float f32x4 __attribute__((ext_vector_type(4)));
typedef unsigned int u32x4 __attribute__((ext_vector_type(4)));
typedef unsigned int u32x2 __attribute__((ext_vector_type(2)));
typedef unsigned short u16;

__device__ __forceinline__ u16 f2bf(float f) {   // round-to-nearest-even
    unsigned int x = __float_as_uint(f);
    x += 0x7fffu + ((x >> 16) & 1u);
    return (u16)(x >> 16);
}
__device__ __forceinline__ void glds16(const void* g, void* l) {
    __builtin_amdgcn_global_load_lds(
        (const __attribute__((address_space(1))) void*)g,
        (__attribute__((address_space(3))) void*)l, 16, 0, 0);
}
// permlane32_swap then permlane16_swap: (a,b) = (w[t][h], w[t+1][h]) -> (dword m0, dword m2)
// of the PV A-fragment (16x16x32 layout: lane(l15,quad) row=l15, k=quad*8..+7).
__device__ __forceinline__ void swap_half(unsigned& a, unsigned& b) {
    u32x2 t = __builtin_amdgcn_permlane32_swap(a, b, false, false);
    t = __builtin_amdgcn_permlane16_swap(t[0], t[1], false, false);
    a = t[0]; b = t[1];
}

// ---------------- prep: z<4: fp32 W[k][n] -> bf16 Wt[n][k]; z>=4: x fp32 -> bf16 copy ----
__global__ __launch_bounds__(256) void prep(const float* __restrict__ W0, const float* __restrict__ W1,
                                            const float* __restrict__ W2, const float* __restrict__ W3,
                                            const float* __restrict__ X,
                                            u16* __restrict__ Wt, u16* __restrict__ Xb) {
    int z = blockIdx.z;
    if (z >= 4) {
        int row = (z - 4) * 1024 + blockIdx.y * 32 + blockIdx.x;
        const float* src = X + (size_t)row * 1024 + threadIdx.x * 4;
        f32x4 v = *(const f32x4*)src;
        u16x4 o; o[0] = f2bf(v[0]); o[1] = f2bf(v[1]); o[2] = f2bf(v[2]); o[3] = f2bf(v[3]);
        *(u16x4*)&Xb[(size_t)row * 1024 + threadIdx.x * 4] = o;
        return;
    }
    __shared__ float T[32][33];
    const float* W = (z == 0) ? W0 : ((z == 1) ? W1 : ((z == 2) ? W2 : W3));
    u16* dst = Wt + (size_t)z * 1024 * 1024;
    int k0 = blockIdx.y * 32, n0 = blockIdx.x * 32;
    int x = threadIdx.x & 31, y0 = threadIdx.x >> 5;
#pragma unroll
    for (int i = 0; i < 4; i++) {
        int y = y0 + i * 8;
        T[y][x] = W[(size_t)(k0 + y) * 1024 + n0 + x];
    }
    __syncthreads();
#pragma unroll
    for (int i = 0; i < 4; i++) {
        int y = y0 + i * 8;
        dst[(size_t)(n0 + y) * 1024 + k0 + x] = f2bf(T[x][y]);
    }
}

// ---------------- GEMM: C[M][Ntot] = A[M][1024] * Bt^T + bias ----------------
// v2: double-buffered LDS + counted s_waitcnt vmcnt(4) (attn-proven schedule).
// Prefetch of K-tile k+1 stays in flight across the whole compute of tile k;
// vmcnt never drains to 0 mid-loop. Q columns (VSPLIT, sel==0) pre-scaled by
// log2(e)/sqrt(d_k) so attn skips the per-element multiply before exp2.
template <bool OF32, bool VSPLIT>
__global__ __launch_bounds__(256) void gemm(
    const u16* __restrict__ Bt,
    const float* __restrict__ b0, const float* __restrict__ b1, const float* __restrict__ b2,
    const u16* __restrict__ A, void* __restrict__ Cptr, u16* __restrict__ Vt, int Ntot)
{
    __shared__ __align__(16) u16 As[2][128 * 32];
    __shared__ __align__(16) u16 Bs[2][128 * 32];
    int tid = threadIdx.x;
    int lane = tid & 63, l15 = lane & 15, quad = lane >> 4;
    int wid = tid >> 6, wm = wid >> 1, wn = wid & 1;
    int m0 = blockIdx.y * 128, n0 = blockIdx.x * 128;
    int sel = n0 >> 10;
    const float* bias = (sel == 0) ? b0 : ((sel == 1) ? b1 : b2);

    f32x4 acc[4][4];
#pragma unroll
    for (int i = 0; i < 4; i++)
#pragma unroll
        for (int j = 0; j < 4; j++) { f32x4 z = {0.f, 0.f, 0.f, 0.f}; acc[i][j] = z; }

    int rr = lane >> 2;
    int cc = (lane & 3) ^ ((rr >> 1) & 3);
    const u16* abase = A  + (size_t)m0 * 1024;
    const u16* bbase = Bt + (size_t)n0 * 1024;
    int fsw = (l15 >> 1) & 3;

    auto stage = [&](int k0, int bsel) {
#pragma unroll
        for (int inst = 0; inst < 2; inst++) {
            int r0 = wid * 32 + inst * 16;
            glds16(&abase[(size_t)(r0 + rr) * 1024 + k0 + cc * 8], &As[bsel][r0 * 32]);
            glds16(&bbase[(size_t)(r0 + rr) * 1024 + k0 + cc * 8], &Bs[bsel][r0 * 32]);
        }
    };

    stage(0, 0);                   // prologue: K-tile 0 -> buf 0 (4 loads in flight)
#pragma unroll 2
    for (int it = 0; it < 32; ++it) {
        int cur = it & 1;
        if (it < 31) {
            stage((it + 1) * 32, cur ^ 1);   // keep 4 more in flight across compute
            asm volatile("s_waitcnt vmcnt(4)\n\ts_barrier" ::: "memory");
        } else {
            asm volatile("s_waitcnt vmcnt(0)\n\ts_barrier" ::: "memory");
        }
        bf16x8 af[4], bf[4];
#pragma unroll
        for (int mt = 0; mt < 4; mt++)
            af[mt] = *(const bf16x8*)&As[cur][(wm * 64 + mt * 16 + l15) * 32 + ((quad ^ fsw) * 8)];
#pragma unroll
        for (int nt = 0; nt < 4; nt++)
            bf[nt] = *(const bf16x8*)&Bs[cur][(wn * 64 + nt * 16 + l15) * 32 + ((quad ^ fsw) * 8)];
#pragma unroll
        for (int mt = 0; mt < 4; mt++)
#pragma unroll
            for (int nt = 0; nt < 4; nt++)
                acc[mt][nt] = __builtin_amdgcn_mfma_f32_16x16x32_bf16(af[mt], bf[nt], acc[mt][nt], 0, 0, 0);
        asm volatile("s_barrier" ::: "memory");   // readers done before buf overwrite
    }
    if (VSPLIT && sel == 2) {
        int b = m0 >> 11;
#pragma unroll
        for (int mt = 0; mt < 4; mt++) {
            int gr = m0 + wm * 64 + mt * 16 + quad * 4;
            int s = gr & 2047;
#pragma unroll
            for (int nt = 0; nt < 4; nt++) {
                int gcl = (n0 & 1023) + wn * 64 + nt * 16 + l15;
                float bb = bias[gcl];
                u16x4 pk;
#pragma unroll
                for (int r = 0; r < 4; r++) pk[r] = f2bf(acc[mt][nt][r] + bb);
                *(u16x4*)&Vt[(size_t)((b * 16 + (gcl >> 6)) * 64 + (gcl & 63)) * 2048 + s] = pk;
            }
        }
        return;
    }
    float qs = (VSPLIT && sel == 0) ? 0.18033688011112f : 1.0f;  // log2(e)/sqrt(64)
#pragma unroll
    for (int mt = 0; mt < 4; mt++) {
        int gr = m0 + wm * 64 + mt * 16 + quad * 4;
#pragma unroll
        for (int nt = 0; nt < 4; nt++) {
            int gc = n0 + wn * 64 + nt * 16 + l15;
            float bb = bias[gc & 1023];
#pragma unroll
            for (int r = 0; r < 4; r++) {
                float v = (acc[mt][nt][r] + bb) * qs;
                if (OF32) ((float*)Cptr)[(size_t)(gr + r) * Ntot + gc] = v;
                else      ((u16*)Cptr)[(size_t)(gr + r) * Ntot + gc] = f2bf(v);
            }
        }
    }
}

// ---------------- MFMA flash attention, v3 ----------------
//  * 32 q-rows per wave (two 16-row fragment sets A/B); K/V frags read once, reused.
//  * Q pre-scaled by log2(e)/sqrt(d_k); exp2 directly.
//  * Counted-vmcnt double-buffer (never drain to 0 mid-loop), XOR chunk swizzle.
// Grid: (16 qtiles of 128 q, 16 heads, 2 batch) = 512 blocks, 256 thr = 2 blocks/CU.
__global__ __launch_bounds__(256, 2) void attn(const u16* __restrict__ QKV, // [B*S][3072]
                                               const u16* __restrict__ Vt,  // [bh*64+d][2048]
                                               u16* __restrict__ O)         // [B*S][1024]
{
    __shared__ __align__(16) u16 Ks[2][64 * 64];  // [buf][j][d], XOR-swizzled chunks
    __shared__ __align__(16) u16 Vs[2][64 * 64];  // [buf][d][j], XOR-swizzled chunks
    const int S = 2048, DQ = 3072;
    int tid = threadIdx.x, wid = tid >> 6, lane = tid & 63;
    int l15 = lane & 15, quad = lane >> 4;
    int qt = blockIdx.x, h = blockIdx.y, b = blockIdx.z;
    const u16* base = QKV + (size_t)b * S * DQ + h * 64;
    const u16* Kb = base + 1024;
    const u16* Vtb = Vt + (size_t)((b * 16 + h) * 64) * 2048;
    int q0 = qt * 128 + wid * 32;

    // Q fragments (B-operand of swapped QK^T): halves A (rows q0..+15) and B (q0+16..+31)
    bf16x8 qA0 = *(const bf16x8*)&base[(size_t)(q0 + l15) * DQ + quad * 8];
    bf16x8 qA1 = *(const bf16x8*)&base[(size_t)(q0 + l15) * DQ + 32 + quad * 8];
    bf16x8 qB0 = *(const bf16x8*)&base[(size_t)(q0 + 16 + l15) * DQ + quad * 8];
    bf16x8 qB1 = *(const bf16x8*)&base[(size_t)(q0 + 16 + l15) * DQ + 32 + quad * 8];

    f32x4 oA[4], oB[4];
#pragma unroll
    for (int i = 0; i < 4; i++) { f32x4 z = {0.f, 0.f, 0.f, 0.f}; oA[i] = z; oB[i] = z; }
    float psA = 0.f, psB = 0.f;   // per-lane partial row-sums for q=l15 (quad-partial in j)

    int rr = lane >> 3;            // row within 8-row glds inst
    int cc = (lane & 7) ^ rr;      // swizzled global chunk (row&7 == rr)
    int fs7 = l15 & 7;             // frag un-swizzle key

    auto stage = [&](int it, int bsel) {
        int kv0 = it << 6;
#pragma unroll
        for (int inst = 0; inst < 2; inst++) {
            int r0 = wid * 16 + inst * 8;
            glds16(&Kb[(size_t)(kv0 + r0 + rr) * DQ + cc * 8], &Ks[bsel][r0 * 64]);
            glds16(&Vtb[(size_t)(r0 + rr) * 2048 + kv0 + cc * 8], &Vs[bsel][r0 * 64]);
        }
    };

    stage(0, 0);                   // prologue: tile 0 -> buf 0 (4 loads in flight)
#pragma unroll 2
    for (int it = 0; it < 32; ++it) {
        int cur = it & 1;
        if (it < 31) {
            stage(it + 1, cur ^ 1);   // 4 more loads; keep them in flight across compute
            asm volatile("s_waitcnt vmcnt(4)\n\ts_barrier" ::: "memory");
        } else {
            asm volatile("s_waitcnt vmcnt(0)\n\ts_barrier" ::: "memory");
        }

        // S^T = K Q^T : row(quad*4+r)=j_local, col(l15)=q ; K frags shared by both halves
        f32x4 sA[4], sB[4];
#pragma unroll
        for (int t = 0; t < 4; t++) { f32x4 z = {0.f, 0.f, 0.f, 0.f}; sA[t] = z; sB[t] = z; }
#pragma unroll
        for (int t = 0; t < 4; t++) {
            bf16x8 kfa = *(const bf16x8*)&Ks[cur][(t * 16 + l15) * 64 + ((quad ^ fs7) * 8)];
            bf16x8 kfb = *(const bf16x8*)&Ks[cur][(t * 16 + l15) * 64 + (((quad + 4) ^ fs7) * 8)];
            sA[t] = __builtin_amdgcn_mfma_f32_16x16x32_bf16(kfa, qA0, sA[t], 0, 0, 0);
            sA[t] = __builtin_amdgcn_mfma_f32_16x16x32_bf16(kfb, qA1, sA[t], 0, 0, 0);
            sB[t] = __builtin_amdgcn_mfma_f32_16x16x32_bf16(kfa, qB0, sB[t], 0, 0, 0);
            sB[t] = __builtin_amdgcn_mfma_f32_16x16x32_bf16(kfb, qB1, sB[t], 0, 0, 0);
        }

        // p = exp2(s) (scale pre-folded into Q); pack pairs into dwords; lane sums
        unsigned wA[4][2], wB[4][2];
#pragma unroll
        for (int t = 0; t < 4; t++) {
            float a0 = __builtin_amdgcn_exp2f(sA[t][0]);
            float a1 = __builtin_amdgcn_exp2f(sA[t][1]);
            float a2 = __builtin_amdgcn_exp2f(sA[t][2]);
            float a3 = __builtin_amdgcn_exp2f(sA[t][3]);
            psA += (a0 + a1) + (a2 + a3);
            asm("v_cvt_pk_bf16_f32 %0, %1, %2" : "=v"(wA[t][0]) : "v"(a0), "v"(a1));
            asm("v_cvt_pk_bf16_f32 %0, %1, %2" : "=v"(wA[t][1]) : "v"(a2), "v"(a3));
            float b0_ = __builtin_amdgcn_exp2f(sB[t][0]);
            float b1_ = __builtin_amdgcn_exp2f(sB[t][1]);
            float b2_ = __builtin_amdgcn_exp2f(sB[t][2]);
            float b3_ = __builtin_amdgcn_exp2f(sB[t][3]);
            psB += (b0_ + b1_) + (b2_ + b3_);
            asm("v_cvt_pk_bf16_f32 %0, %1, %2" : "=v"(wB[t][0]) : "v"(b0_), "v"(b1_));
            asm("v_cvt_pk_bf16_f32 %0, %1, %2" : "=v"(wB[t][1]) : "v"(b2_), "v"(b3_));
        }
        // in-register redistribution to PV A-fragments, per half
        unsigned a0 = wA[0][0], a2 = wA[1][0]; swap_half(a0, a2);
        unsigned a1 = wA[0][1], a3 = wA[1][1]; swap_half(a1, a3);
        unsigned c0 = wA[2][0], c2 = wA[3][0]; swap_half(c0, c2);
        unsigned c1 = wA[2][1], c3 = wA[3][1]; swap_half(c1, c3);
        u32x4 pdA0 = {a0, a1, a2, a3};
        u32x4 pdA1 = {c0, c1, c2, c3};
        bf16x8 pfA0 = *(bf16x8*)&pdA0;   // P_A[q=l15][j = quad*8 .. +7]
        bf16x8 pfA1 = *(bf16x8*)&pdA1;   // P_A[q=l15][j = 32+quad*8 .. +7]
        unsigned d0 = wB[0][0], d2 = wB[1][0]; swap_half(d0, d2);
        unsigned d1 = wB[0][1], d3 = wB[1][1]; swap_half(d1, d3);
        unsigned e0 = wB[2][0], e2 = wB[3][0]; swap_half(e0, e2);
        unsigned e1 = wB[2][1], e3 = wB[3][1]; swap_half(e1, e3);
        u32x4 pdB0 = {d0, d1, d2, d3};
        u32x4 pdB1 = {e0, e1, e2, e3};
        bf16x8 pfB0 = *(bf16x8*)&pdB0;
        bf16x8 pfB1 = *(bf16x8*)&pdB1;

        // O += P V : V frags shared by both halves
#pragma unroll
        for (int dt = 0; dt < 4; dt++) {
            bf16x8 vfa = *(const bf16x8*)&Vs[cur][(dt * 16 + l15) * 64 + ((quad ^ fs7) * 8)];
            bf16x8 vfb = *(const bf16x8*)&Vs[cur][(dt * 16 + l15) * 64 + (((quad + 4) ^ fs7) * 8)];
            oA[dt] = __builtin_amdgcn_mfma_f32_16x16x32_bf16(pfA0, vfa, oA[dt], 0, 0, 0);
            oA[dt] = __builtin_amdgcn_mfma_f32_16x16x32_bf16(pfA1, vfb, oA[dt], 0, 0, 0);
            oB[dt] = __builtin_amdgcn_mfma_f32_16x16x32_bf16(pfB0, vfa, oB[dt], 0, 0, 0);
            oB[dt] = __builtin_amdgcn_mfma_f32_16x16x32_bf16(pfB1, vfb, oB[dt], 0, 0, 0);
        }
        asm volatile("s_barrier" ::: "memory");   // readers done before buf overwrite
    }

    // denominators: reduce quad-partials; lane sum is full row-sum for q=l15
    psA += __shfl_xor(psA, 16);
    psA += __shfl_xor(psA, 32);
    psB += __shfl_xor(psB, 16);
    psB += __shfl_xor(psB, 32);
#pragma unroll
    for (int r = 0; r < 4; r++) {
        float invA = 1.0f / __shfl(psA, quad * 4 + r);
        size_t rowA = (size_t)(b * S + q0 + quad * 4 + r);
#pragma unroll
        for (int dt = 0; dt < 4; dt++)
            O[rowA * 1024 + h * 64 + dt * 16 + l15] = f2bf(oA[dt][r] * invA);
        float invB = 1.0f / __shfl(psB, quad * 4 + r);
        size_t rowB = rowA + 16;
#pragma unroll
        for (int dt = 0; dt < 4; dt++)
            O[rowB * 1024 + h * 64 + dt * 16 + l15] = f2bf(oB[dt][r] * invB);
    }
}

extern "C" void kernel_launch(void* const* d_in, const int* in_sizes, int n_in,
                              void* d_out, int out_size, void* d_ws, size_t ws_size,
                              hipStream_t stream) {
    const float* x  = (const float*)d_in[0];
    const float* wq = (const float*)d_in[1];
    const float* bq = (const float*)d_in[2];
    const float* wk = (const float*)d_in[3];
    const float* bk = (const float*)d_in[4];
    const float* wv = (const float*)d_in[5];
    const float* bv = (const float*)d_in[6];
    const float* wo = (const float*)d_in[7];
    const float* bo = (const float*)d_in[8];
    float* out = (float*)d_out;

    u16* qkv  = (u16*)d_ws;
    u16* obuf = qkv  + (size_t)4096 * 3072;
    u16* vt   = obuf + (size_t)4096 * 1024;
    u16* wt   = vt   + (size_t)2048 * 2048;
    u16* xb   = wt   + (size_t)4 * 1024 * 1024;

    dim3 tb(256);
    prep<<<dim3(32, 32, 8), tb, 0, stream>>>(wq, wk, wv, wo, x, wt, xb);
    gemm<false, true><<<dim3(24, 32), tb, 0, stream>>>(wt, bq, bk, bv, xb, qkv, vt, 3072);
    attn<<<dim3(16, 16, 2), tb, 0, stream>>>(qkv, vt, obuf);
    gemm<true, false><<<dim3(8, 32), tb, 0, stream>>>(wt + (size_t)3 * 1024 * 1024,
                                                      bo, bo, bo, obuf, out, (u16*)nullptr, 1024);
}

// Round 4
// 195.038 us; speedup vs baseline: 1.0568x; 1.0568x over previous
//
#include <hip/hip_runtime.h>
#include <hip/hip_bf16.h>
#include <math.h>

typedef __bf16 bf16x8 __attribute__((ext_vector_type(8)));
typedef unsigned short u16x8 __attribute__((ext_vector_type(8)));
typedef unsigned short u16x4 __attribute__((ext_vector_type(4)));
typedef float f32x4 __attribute__((ext_vector_type(4)));
typedef unsigned int u32x4 __attribute__((ext_vector_type(4)));
typedef unsigned int u32x2 __attribute__((ext_vector_type(2)));
typedef unsigned short u16;

__device__ __forceinline__ u16 f2bf(float f) {   // round-to-nearest-even
    unsigned int x = __float_as_uint(f);
    x += 0x7fffu + ((x >> 16) & 1u);
    return (u16)(x >> 16);
}
__device__ __forceinline__ void glds16(const void* g, void* l) {
    __builtin_amdgcn_global_load_lds(
        (const __attribute__((address_space(1))) void*)g,
        (__attribute__((address_space(3))) void*)l, 16, 0, 0);
}
// permlane32_swap then permlane16_swap: (a,b) = (w[t][h], w[t+1][h]) -> (dword m0, dword m2)
// of the PV A-fragment (16x16x32 layout: lane(l15,quad) row=l15, k=quad*8..+7).
__device__ __forceinline__ void swap_half(unsigned& a, unsigned& b) {
    u32x2 t = __builtin_amdgcn_permlane32_swap(a, b, false, false);
    t = __builtin_amdgcn_permlane16_swap(t[0], t[1], false, false);
    a = t[0]; b = t[1];
}

// ---------------- prep: z<4: fp32 W[k][n] -> bf16 Wt[n][k]; z>=4: x fp32 -> bf16 copy ----
__global__ __launch_bounds__(256) void prep(const float* __restrict__ W0, const float* __restrict__ W1,
                                            const float* __restrict__ W2, const float* __restrict__ W3,
                                            const float* __restrict__ X,
                                            u16* __restrict__ Wt, u16* __restrict__ Xb) {
    int z = blockIdx.z;
    if (z >= 4) {
        int row = (z - 4) * 1024 + blockIdx.y * 32 + blockIdx.x;
        const float* src = X + (size_t)row * 1024 + threadIdx.x * 4;
        f32x4 v = *(const f32x4*)src;
        u16x4 o; o[0] = f2bf(v[0]); o[1] = f2bf(v[1]); o[2] = f2bf(v[2]); o[3] = f2bf(v[3]);
        *(u16x4*)&Xb[(size_t)row * 1024 + threadIdx.x * 4] = o;
        return;
    }
    __shared__ float T[32][33];
    const float* W = (z == 0) ? W0 : ((z == 1) ? W1 : ((z == 2) ? W2 : W3));
    u16* dst = Wt + (size_t)z * 1024 * 1024;
    int k0 = blockIdx.y * 32, n0 = blockIdx.x * 32;
    int x = threadIdx.x & 31, y0 = threadIdx.x >> 5;
#pragma unroll
    for (int i = 0; i < 4; i++) {
        int y = y0 + i * 8;
        T[y][x] = W[(size_t)(k0 + y) * 1024 + n0 + x];
    }
    __syncthreads();
#pragma unroll
    for (int i = 0; i < 4; i++) {
        int y = y0 + i * 8;
        dst[(size_t)(n0 + y) * 1024 + k0 + x] = f2bf(T[x][y]);
    }
}

// ---------------- gemm256: QKV GEMM, 256x256 tile, BK=64, 8-wave 8-phase schedule ----
// C[4096][3072] = A[4096][1024] * Bt^T + bias; Q cols pre-scaled; V cols -> Vt transposed.
// m201-style schedule: per K-tile, 4 dual-barrier phases {ds_read af ; stage one half-tile
// of K-tile it+1 into other buffer ; s_barrier ; lgkmcnt(0) ; setprio(1) 16 MFMA setprio(0);
// s_barrier}. vmcnt(2) ONCE per K-tile (phase 0), never 0 mid-loop. XOR chunk swizzle
// (attn-verified, conflict-free): LDS[row][c] = global[row][c ^ (row&7)], chunks of 8 u16.
__global__ __launch_bounds__(512, 2) void gemm256(
    const u16* __restrict__ Bt,
    const float* __restrict__ b0, const float* __restrict__ b1, const float* __restrict__ b2,
    const u16* __restrict__ A, u16* __restrict__ C, u16* __restrict__ Vt)
{
    __shared__ __align__(16) u16 As[2][256 * 64];
    __shared__ __align__(16) u16 Bs[2][256 * 64];
    int tid = threadIdx.x;
    int lane = tid & 63, l15 = lane & 15, quad = lane >> 4;
    int wid = tid >> 6;                 // 0..7
    int wm = wid >> 2, wn = wid & 3;    // 2 (M) x 4 (N)
    int m0 = blockIdx.y * 256, n0 = blockIdx.x * 256;
    int sel = n0 >> 10;                 // 0=Q 1=K 2=V (256-tiles never straddle)
    const float* bias = (sel == 0) ? b0 : ((sel == 1) ? b1 : b2);

    f32x4 acc[8][4];
#pragma unroll
    for (int i = 0; i < 8; i++)
#pragma unroll
        for (int j = 0; j < 4; j++) { f32x4 z = {0.f, 0.f, 0.f, 0.f}; acc[i][j] = z; }

    int rr = lane >> 3;                 // row within 8-row glds inst
    int cc = (lane & 7) ^ rr;           // pre-swizzled global chunk
    int fs7 = l15 & 7;                  // frag un-swizzle key
    const u16* abase = A  + (size_t)m0 * 1024;
    const u16* bbase = Bt + (size_t)n0 * 1024;

    // stage half-tile hp (0:A rows0-127, 1:A rows128-255, 2:B rows0-127, 3:B rows128-255)
    // of K-tile kt into buffer buf. 2 glds16 per thread (wave w covers rows w*16..+16).
    auto stage = [&](int kt, int hp, int buf) {
        const u16* gsrc = (hp < 2) ? abase : bbase;
        u16* ldst = (hp < 2) ? As[buf] : Bs[buf];
        int k0 = kt * 64;
        int hbase = (hp & 1) * 128;
#pragma unroll
        for (int inst = 0; inst < 2; inst++) {
            int r0 = hbase + wid * 16 + inst * 8;
            glds16(&gsrc[(size_t)(r0 + rr) * 1024 + k0 + cc * 8], &ldst[r0 * 64]);
        }
    };

    // prologue: K-tile 0 -> buf 0 (8 loads in flight)
#pragma unroll
    for (int hp = 0; hp < 4; hp++) stage(0, hp, 0);

#pragma unroll 2
    for (int it = 0; it < 16; ++it) {
        int c = it & 1;
        // ---- phase 0: stage A-h0(next); wait current K-tile landed; bf + af[0,1]; MFMA ----
        if (it < 15) {
            stage(it + 1, 0, c ^ 1);
            asm volatile("s_waitcnt vmcnt(2)");
        } else {
            asm volatile("s_waitcnt vmcnt(0)");
        }
        __builtin_amdgcn_s_barrier();          // all waves' K-tile-it loads landed
        bf16x8 bfr[4][2];
#pragma unroll
        for (int nt = 0; nt < 4; nt++)
#pragma unroll
            for (int h = 0; h < 2; h++)
                bfr[nt][h] = *(const bf16x8*)&Bs[c][(wn * 64 + nt * 16 + l15) * 64 +
                                                    ((((h << 2) | quad) ^ fs7) * 8)];
        {
            bf16x8 af[2][2];
#pragma unroll
            for (int m = 0; m < 2; m++)
#pragma unroll
                for (int h = 0; h < 2; h++)
                    af[m][h] = *(const bf16x8*)&As[c][(wm * 128 + m * 16 + l15) * 64 +
                                                      ((((h << 2) | quad) ^ fs7) * 8)];
            asm volatile("s_waitcnt lgkmcnt(0)");
            __builtin_amdgcn_sched_barrier(0);
            __builtin_amdgcn_s_setprio(1);
#pragma unroll
            for (int m = 0; m < 2; m++)
#pragma unroll
                for (int nt = 0; nt < 4; nt++)
#pragma unroll
                    for (int h = 0; h < 2; h++)
                        acc[m][nt] = __builtin_amdgcn_mfma_f32_16x16x32_bf16(
                            af[m][h], bfr[nt][h], acc[m][nt], 0, 0, 0);
            __builtin_amdgcn_s_setprio(0);
            __builtin_amdgcn_s_barrier();
        }
        // ---- phases 1..3: {ds_read af-pair ; stage next half-tile ; barrier ; MFMA ; barrier}
#pragma unroll
        for (int p = 1; p < 4; p++) {
            bf16x8 af[2][2];
#pragma unroll
            for (int m = 0; m < 2; m++)
#pragma unroll
                for (int h = 0; h < 2; h++)
                    af[m][h] = *(const bf16x8*)&As[c][(wm * 128 + (p * 2 + m) * 16 + l15) * 64 +
                                                      ((((h << 2) | quad) ^ fs7) * 8)];
            if (it < 15) stage(it + 1, p, c ^ 1);
            __builtin_amdgcn_s_barrier();
            asm volatile("s_waitcnt lgkmcnt(0)");
            __builtin_amdgcn_sched_barrier(0);
            __builtin_amdgcn_s_setprio(1);
#pragma unroll
            for (int m = 0; m < 2; m++)
#pragma unroll
                for (int nt = 0; nt < 4; nt++)
#pragma unroll
                    for (int h = 0; h < 2; h++)
                        acc[p * 2 + m][nt] = __builtin_amdgcn_mfma_f32_16x16x32_bf16(
                            af[m][h], bfr[nt][h], acc[p * 2 + m][nt], 0, 0, 0);
            __builtin_amdgcn_s_setprio(0);
            __builtin_amdgcn_s_barrier();      // gates next iter's stage into buf c
        }
    }

    // ---- epilogue: C/D layout col=l15, row=quad*4+reg ----
    if (sel == 2) {
        int b = m0 >> 11;
#pragma unroll
        for (int mt = 0; mt < 8; mt++) {
            int gr = m0 + wm * 128 + mt * 16 + quad * 4;
            int s = gr & 2047;
#pragma unroll
            for (int nt = 0; nt < 4; nt++) {
                int gcl = (n0 & 1023) + wn * 64 + nt * 16 + l15;   // = h*64+d
                float bb = bias[gcl];
                u16x4 pk;
#pragma unroll
                for (int r = 0; r < 4; r++) pk[r] = f2bf(acc[mt][nt][r] + bb);
                *(u16x4*)&Vt[(size_t)((b * 16 + (gcl >> 6)) * 64 + (gcl & 63)) * 2048 + s] = pk;
            }
        }
        return;
    }
    float qs = (sel == 0) ? 0.18033688011112f : 1.0f;  // log2(e)/sqrt(64) folded into Q
#pragma unroll
    for (int mt = 0; mt < 8; mt++) {
        int gr = m0 + wm * 128 + mt * 16 + quad * 4;
#pragma unroll
        for (int nt = 0; nt < 4; nt++) {
            int gc = n0 + wn * 64 + nt * 16 + l15;
            float bb = bias[gc & 1023];
#pragma unroll
            for (int r = 0; r < 4; r++)
                C[(size_t)(gr + r) * 3072 + gc] = f2bf((acc[mt][nt][r] + bb) * qs);
        }
    }
}

// ---------------- GEMM (proj): 128x128 tile, R2 single-buffer structure ----------------
template <bool OF32, bool VSPLIT>
__global__ __launch_bounds__(256) void gemm(
    const u16* __restrict__ Bt,
    const float* __restrict__ b0, const float* __restrict__ b1, const float* __restrict__ b2,
    const u16* __restrict__ A, void* __restrict__ Cptr, u16* __restrict__ Vt, int Ntot)
{
    __shared__ __align__(16) u16 As[128 * 32];
    __shared__ __align__(16) u16 Bs[128 * 32];
    int tid = threadIdx.x;
    int lane = tid & 63, l15 = lane & 15, quad = lane >> 4;
    int wid = tid >> 6, wm = wid >> 1, wn = wid & 1;
    int m0 = blockIdx.y * 128, n0 = blockIdx.x * 128;
    int sel = n0 >> 10;
    const float* bias = (sel == 0) ? b0 : ((sel == 1) ? b1 : b2);

    f32x4 acc[4][4];
#pragma unroll
    for (int i = 0; i < 4; i++)
#pragma unroll
        for (int j = 0; j < 4; j++) { f32x4 z = {0.f, 0.f, 0.f, 0.f}; acc[i][j] = z; }

    int rr = lane >> 2;
    int cc = (lane & 3) ^ ((rr >> 1) & 3);
    const u16* abase = A  + (size_t)m0 * 1024;
    const u16* bbase = Bt + (size_t)n0 * 1024;
    int fsw = (l15 >> 1) & 3;

    for (int k0 = 0; k0 < 1024; k0 += 32) {
#pragma unroll
        for (int inst = 0; inst < 2; inst++) {
            int r0 = wid * 32 + inst * 16;
            glds16(&abase[(size_t)(r0 + rr) * 1024 + k0 + cc * 8], &As[r0 * 32]);
            glds16(&bbase[(size_t)(r0 + rr) * 1024 + k0 + cc * 8], &Bs[r0 * 32]);
        }
        __syncthreads();
        bf16x8 af[4], bf[4];
#pragma unroll
        for (int mt = 0; mt < 4; mt++)
            af[mt] = *(const bf16x8*)&As[(wm * 64 + mt * 16 + l15) * 32 + ((quad ^ fsw) * 8)];
#pragma unroll
        for (int nt = 0; nt < 4; nt++)
            bf[nt] = *(const bf16x8*)&Bs[(wn * 64 + nt * 16 + l15) * 32 + ((quad ^ fsw) * 8)];
#pragma unroll
        for (int mt = 0; mt < 4; mt++)
#pragma unroll
            for (int nt = 0; nt < 4; nt++)
                acc[mt][nt] = __builtin_amdgcn_mfma_f32_16x16x32_bf16(af[mt], bf[nt], acc[mt][nt], 0, 0, 0);
        __syncthreads();
    }
    if (VSPLIT && sel == 2) {
        int b = m0 >> 11;
#pragma unroll
        for (int mt = 0; mt < 4; mt++) {
            int gr = m0 + wm * 64 + mt * 16 + quad * 4;
            int s = gr & 2047;
#pragma unroll
            for (int nt = 0; nt < 4; nt++) {
                int gcl = (n0 & 1023) + wn * 64 + nt * 16 + l15;
                float bb = bias[gcl];
                u16x4 pk;
#pragma unroll
                for (int r = 0; r < 4; r++) pk[r] = f2bf(acc[mt][nt][r] + bb);
                *(u16x4*)&Vt[(size_t)((b * 16 + (gcl >> 6)) * 64 + (gcl & 63)) * 2048 + s] = pk;
            }
        }
        return;
    }
    float qs = (VSPLIT && sel == 0) ? 0.18033688011112f : 1.0f;
#pragma unroll
    for (int mt = 0; mt < 4; mt++) {
        int gr = m0 + wm * 64 + mt * 16 + quad * 4;
#pragma unroll
        for (int nt = 0; nt < 4; nt++) {
            int gc = n0 + wn * 64 + nt * 16 + l15;
            float bb = bias[gc & 1023];
#pragma unroll
            for (int r = 0; r < 4; r++) {
                float v = (acc[mt][nt][r] + bb) * qs;
                if (OF32) ((float*)Cptr)[(size_t)(gr + r) * Ntot + gc] = v;
                else      ((u16*)Cptr)[(size_t)(gr + r) * Ntot + gc] = f2bf(v);
            }
        }
    }
}

// ---------------- MFMA flash attention (unchanged from R2) ----------------
__global__ __launch_bounds__(256, 2) void attn(const u16* __restrict__ QKV, // [B*S][3072]
                                               const u16* __restrict__ Vt,  // [bh*64+d][2048]
                                               u16* __restrict__ O)         // [B*S][1024]
{
    __shared__ __align__(16) u16 Ks[2][64 * 64];  // [buf][j][d], XOR-swizzled chunks
    __shared__ __align__(16) u16 Vs[2][64 * 64];  // [buf][d][j], XOR-swizzled chunks
    const int S = 2048, DQ = 3072;
    int tid = threadIdx.x, wid = tid >> 6, lane = tid & 63;
    int l15 = lane & 15, quad = lane >> 4;
    int qt = blockIdx.x, h = blockIdx.y, b = blockIdx.z;
    const u16* base = QKV + (size_t)b * S * DQ + h * 64;
    const u16* Kb = base + 1024;
    const u16* Vtb = Vt + (size_t)((b * 16 + h) * 64) * 2048;
    int q0 = qt * 128 + wid * 32;

    bf16x8 qA0 = *(const bf16x8*)&base[(size_t)(q0 + l15) * DQ + quad * 8];
    bf16x8 qA1 = *(const bf16x8*)&base[(size_t)(q0 + l15) * DQ + 32 + quad * 8];
    bf16x8 qB0 = *(const bf16x8*)&base[(size_t)(q0 + 16 + l15) * DQ + quad * 8];
    bf16x8 qB1 = *(const bf16x8*)&base[(size_t)(q0 + 16 + l15) * DQ + 32 + quad * 8];

    f32x4 oA[4], oB[4];
#pragma unroll
    for (int i = 0; i < 4; i++) { f32x4 z = {0.f, 0.f, 0.f, 0.f}; oA[i] = z; oB[i] = z; }
    float psA = 0.f, psB = 0.f;

    int rr = lane >> 3;
    int cc = (lane & 7) ^ rr;
    int fs7 = l15 & 7;

    auto stage = [&](int it, int bsel) {
        int kv0 = it << 6;
#pragma unroll
        for (int inst = 0; inst < 2; inst++) {
            int r0 = wid * 16 + inst * 8;
            glds16(&Kb[(size_t)(kv0 + r0 + rr) * DQ + cc * 8], &Ks[bsel][r0 * 64]);
            glds16(&Vtb[(size_t)(r0 + rr) * 2048 + kv0 + cc * 8], &Vs[bsel][r0 * 64]);
        }
    };

    stage(0, 0);
#pragma unroll 2
    for (int it = 0; it < 32; ++it) {
        int cur = it & 1;
        if (it < 31) {
            stage(it + 1, cur ^ 1);
            asm volatile("s_waitcnt vmcnt(4)\n\ts_barrier" ::: "memory");
        } else {
            asm volatile("s_waitcnt vmcnt(0)\n\ts_barrier" ::: "memory");
        }

        f32x4 sA[4], sB[4];
#pragma unroll
        for (int t = 0; t < 4; t++) { f32x4 z = {0.f, 0.f, 0.f, 0.f}; sA[t] = z; sB[t] = z; }
#pragma unroll
        for (int t = 0; t < 4; t++) {
            bf16x8 kfa = *(const bf16x8*)&Ks[cur][(t * 16 + l15) * 64 + ((quad ^ fs7) * 8)];
            bf16x8 kfb = *(const bf16x8*)&Ks[cur][(t * 16 + l15) * 64 + (((quad + 4) ^ fs7) * 8)];
            sA[t] = __builtin_amdgcn_mfma_f32_16x16x32_bf16(kfa, qA0, sA[t], 0, 0, 0);
            sA[t] = __builtin_amdgcn_mfma_f32_16x16x32_bf16(kfb, qA1, sA[t], 0, 0, 0);
            sB[t] = __builtin_amdgcn_mfma_f32_16x16x32_bf16(kfa, qB0, sB[t], 0, 0, 0);
            sB[t] = __builtin_amdgcn_mfma_f32_16x16x32_bf16(kfb, qB1, sB[t], 0, 0, 0);
        }

        unsigned wA[4][2], wB[4][2];
#pragma unroll
        for (int t = 0; t < 4; t++) {
            float a0 = __builtin_amdgcn_exp2f(sA[t][0]);
            float a1 = __builtin_amdgcn_exp2f(sA[t][1]);
            float a2 = __builtin_amdgcn_exp2f(sA[t][2]);
            float a3 = __builtin_amdgcn_exp2f(sA[t][3]);
            psA += (a0 + a1) + (a2 + a3);
            asm("v_cvt_pk_bf16_f32 %0, %1, %2" : "=v"(wA[t][0]) : "v"(a0), "v"(a1));
            asm("v_cvt_pk_bf16_f32 %0, %1, %2" : "=v"(wA[t][1]) : "v"(a2), "v"(a3));
            float b0_ = __builtin_amdgcn_exp2f(sB[t][0]);
            float b1_ = __builtin_amdgcn_exp2f(sB[t][1]);
            float b2_ = __builtin_amdgcn_exp2f(sB[t][2]);
            float b3_ = __builtin_amdgcn_exp2f(sB[t][3]);
            psB += (b0_ + b1_) + (b2_ + b3_);
            asm("v_cvt_pk_bf16_f32 %0, %1, %2" : "=v"(wB[t][0]) : "v"(b0_), "v"(b1_));
            asm("v_cvt_pk_bf16_f32 %0, %1, %2" : "=v"(wB[t][1]) : "v"(b2_), "v"(b3_));
        }
        unsigned a0 = wA[0][0], a2 = wA[1][0]; swap_half(a0, a2);
        unsigned a1 = wA[0][1], a3 = wA[1][1]; swap_half(a1, a3);
        unsigned c0 = wA[2][0], c2 = wA[3][0]; swap_half(c0, c2);
        unsigned c1 = wA[2][1], c3 = wA[3][1]; swap_half(c1, c3);
        u32x4 pdA0 = {a0, a1, a2, a3};
        u32x4 pdA1 = {c0, c1, c2, c3};
        bf16x8 pfA0 = *(bf16x8*)&pdA0;
        bf16x8 pfA1 = *(bf16x8*)&pdA1;
        unsigned d0 = wB[0][0], d2 = wB[1][0]; swap_half(d0, d2);
        unsigned d1 = wB[0][1], d3 = wB[1][1]; swap_half(d1, d3);
        unsigned e0 = wB[2][0], e2 = wB[3][0]; swap_half(e0, e2);
        unsigned e1 = wB[2][1], e3 = wB[3][1]; swap_half(e1, e3);
        u32x4 pdB0 = {d0, d1, d2, d3};
        u32x4 pdB1 = {e0, e1, e2, e3};
        bf16x8 pfB0 = *(bf16x8*)&pdB0;
        bf16x8 pfB1 = *(bf16x8*)&pdB1;

#pragma unroll
        for (int dt = 0; dt < 4; dt++) {
            bf16x8 vfa = *(const bf16x8*)&Vs[cur][(dt * 16 + l15) * 64 + ((quad ^ fs7) * 8)];
            bf16x8 vfb = *(const bf16x8*)&Vs[cur][(dt * 16 + l15) * 64 + (((quad + 4) ^ fs7) * 8)];
            oA[dt] = __builtin_amdgcn_mfma_f32_16x16x32_bf16(pfA0, vfa, oA[dt], 0, 0, 0);
            oA[dt] = __builtin_amdgcn_mfma_f32_16x16x32_bf16(pfA1, vfb, oA[dt], 0, 0, 0);
            oB[dt] = __builtin_amdgcn_mfma_f32_16x16x32_bf16(pfB0, vfa, oB[dt], 0, 0, 0);
            oB[dt] = __builtin_amdgcn_mfma_f32_16x16x32_bf16(pfB1, vfb, oB[dt], 0, 0, 0);
        }
        asm volatile("s_barrier" ::: "memory");
    }

    psA += __shfl_xor(psA, 16);
    psA += __shfl_xor(psA, 32);
    psB += __shfl_xor(psB, 16);
    psB += __shfl_xor(psB, 32);
#pragma unroll
    for (int r = 0; r < 4; r++) {
        float invA = 1.0f / __shfl(psA, quad * 4 + r);
        size_t rowA = (size_t)(b * S + q0 + quad * 4 + r);
#pragma unroll
        for (int dt = 0; dt < 4; dt++)
            O[rowA * 1024 + h * 64 + dt * 16 + l15] = f2bf(oA[dt][r] * invA);
        float invB = 1.0f / __shfl(psB, quad * 4 + r);
        size_t rowB = rowA + 16;
#pragma unroll
        for (int dt = 0; dt < 4; dt++)
            O[rowB * 1024 + h * 64 + dt * 16 + l15] = f2bf(oB[dt][r] * invB);
    }
}

extern "C" void kernel_launch(void* const* d_in, const int* in_sizes, int n_in,
                              void* d_out, int out_size, void* d_ws, size_t ws_size,
                              hipStream_t stream) {
    const float* x  = (const float*)d_in[0];
    const float* wq = (const float*)d_in[1];
    const float* bq = (const float*)d_in[2];
    const float* wk = (const float*)d_in[3];
    const float* bk = (const float*)d_in[4];
    const float* wv = (const float*)d_in[5];
    const float* bv = (const float*)d_in[6];
    const float* wo = (const float*)d_in[7];
    const float* bo = (const float*)d_in[8];
    float* out = (float*)d_out;

    u16* qkv  = (u16*)d_ws;
    u16* obuf = qkv  + (size_t)4096 * 3072;
    u16* vt   = obuf + (size_t)4096 * 1024;
    u16* wt   = vt   + (size_t)2048 * 2048;
    u16* xb   = wt   + (size_t)4 * 1024 * 1024;

    dim3 tb(256);
    prep<<<dim3(32, 32, 8), tb, 0, stream>>>(wq, wk, wv, wo, x, wt, xb);
    gemm256<<<dim3(12, 16), dim3(512), 0, stream>>>(wt, bq, bk, bv, xb, qkv, vt);
    attn<<<dim3(16, 16, 2), tb, 0, stream>>>(qkv, vt, obuf);
    gemm<true, false><<<dim3(8, 32), tb, 0, stream>>>(wt + (size_t)3 * 1024 * 1024,
                                                      bo, bo, bo, obuf, out, (u16*)nullptr, 1024);
}

// Round 5
// 193.192 us; speedup vs baseline: 1.0669x; 1.0096x over previous
//
#include <hip/hip_runtime.h>
#include <hip/hip_bf16.h>
#include <math.h>

typedef __bf16 bf16x8 __attribute__((ext_vector_type(8)));
typedef unsigned short u16x8 __attribute__((ext_vector_type(8)));
typedef unsigned short u16x4 __attribute__((ext_vector_type(4)));
typedef float f32x4 __attribute__((ext_vector_type(4)));
typedef unsigned int u32x4 __attribute__((ext_vector_type(4)));
typedef unsigned int u32x2 __attribute__((ext_vector_type(2)));
typedef unsigned short u16;

__device__ __forceinline__ u16 f2bf(float f) {   // round-to-nearest-even
    unsigned int x = __float_as_uint(f);
    x += 0x7fffu + ((x >> 16) & 1u);
    return (u16)(x >> 16);
}
__device__ __forceinline__ void glds16(const void* g, void* l) {
    __builtin_amdgcn_global_load_lds(
        (const __attribute__((address_space(1))) void*)g,
        (__attribute__((address_space(3))) void*)l, 16, 0, 0);
}
// permlane32_swap then permlane16_swap: (a,b) = (w[t][h], w[t+1][h]) -> (dword m0, dword m2)
// of the PV A-fragment (16x16x32 layout: lane(l15,quad) row=l15, k=quad*8..+7).
__device__ __forceinline__ void swap_half(unsigned& a, unsigned& b) {
    u32x2 t = __builtin_amdgcn_permlane32_swap(a, b, false, false);
    t = __builtin_amdgcn_permlane16_swap(t[0], t[1], false, false);
    a = t[0]; b = t[1];
}

// ---------------- prep: z<4: fp32 W[k][n] -> bf16 Wt[n][k]; z>=4: x fp32 -> bf16 copy ----
__global__ __launch_bounds__(256) void prep(const float* __restrict__ W0, const float* __restrict__ W1,
                                            const float* __restrict__ W2, const float* __restrict__ W3,
                                            const float* __restrict__ X,
                                            u16* __restrict__ Wt, u16* __restrict__ Xb) {
    int z = blockIdx.z;
    if (z >= 4) {
        int row = (z - 4) * 1024 + blockIdx.y * 32 + blockIdx.x;
        const float* src = X + (size_t)row * 1024 + threadIdx.x * 4;
        f32x4 v = *(const f32x4*)src;
        u16x4 o; o[0] = f2bf(v[0]); o[1] = f2bf(v[1]); o[2] = f2bf(v[2]); o[3] = f2bf(v[3]);
        *(u16x4*)&Xb[(size_t)row * 1024 + threadIdx.x * 4] = o;
        return;
    }
    __shared__ float T[32][33];
    const float* W = (z == 0) ? W0 : ((z == 1) ? W1 : ((z == 2) ? W2 : W3));
    u16* dst = Wt + (size_t)z * 1024 * 1024;
    int k0 = blockIdx.y * 32, n0 = blockIdx.x * 32;
    int x = threadIdx.x & 31, y0 = threadIdx.x >> 5;
#pragma unroll
    for (int i = 0; i < 4; i++) {
        int y = y0 + i * 8;
        T[y][x] = W[(size_t)(k0 + y) * 1024 + n0 + x];
    }
    __syncthreads();
#pragma unroll
    for (int i = 0; i < 4; i++) {
        int y = y0 + i * 8;
        dst[(size_t)(n0 + y) * 1024 + k0 + x] = f2bf(T[x][y]);
    }
}

// ---------------- gemm256: QKV GEMM, 256x256 tile, BK=64, 8-wave 8-phase schedule ----
// (unchanged from R4 — verified) m201-style schedule: per K-tile, 4 dual-barrier phases.
__global__ __launch_bounds__(512, 2) void gemm256(
    const u16* __restrict__ Bt,
    const float* __restrict__ b0, const float* __restrict__ b1, const float* __restrict__ b2,
    const u16* __restrict__ A, u16* __restrict__ C, u16* __restrict__ Vt)
{
    __shared__ __align__(16) u16 As[2][256 * 64];
    __shared__ __align__(16) u16 Bs[2][256 * 64];
    int tid = threadIdx.x;
    int lane = tid & 63, l15 = lane & 15, quad = lane >> 4;
    int wid = tid >> 6;                 // 0..7
    int wm = wid >> 2, wn = wid & 3;    // 2 (M) x 4 (N)
    int m0 = blockIdx.y * 256, n0 = blockIdx.x * 256;
    int sel = n0 >> 10;                 // 0=Q 1=K 2=V (256-tiles never straddle)
    const float* bias = (sel == 0) ? b0 : ((sel == 1) ? b1 : b2);

    f32x4 acc[8][4];
#pragma unroll
    for (int i = 0; i < 8; i++)
#pragma unroll
        for (int j = 0; j < 4; j++) { f32x4 z = {0.f, 0.f, 0.f, 0.f}; acc[i][j] = z; }

    int rr = lane >> 3;                 // row within 8-row glds inst
    int cc = (lane & 7) ^ rr;           // pre-swizzled global chunk
    int fs7 = l15 & 7;                  // frag un-swizzle key
    const u16* abase = A  + (size_t)m0 * 1024;
    const u16* bbase = Bt + (size_t)n0 * 1024;

    auto stage = [&](int kt, int hp, int buf) {
        const u16* gsrc = (hp < 2) ? abase : bbase;
        u16* ldst = (hp < 2) ? As[buf] : Bs[buf];
        int k0 = kt * 64;
        int hbase = (hp & 1) * 128;
#pragma unroll
        for (int inst = 0; inst < 2; inst++) {
            int r0 = hbase + wid * 16 + inst * 8;
            glds16(&gsrc[(size_t)(r0 + rr) * 1024 + k0 + cc * 8], &ldst[r0 * 64]);
        }
    };

#pragma unroll
    for (int hp = 0; hp < 4; hp++) stage(0, hp, 0);

#pragma unroll 2
    for (int it = 0; it < 16; ++it) {
        int c = it & 1;
        if (it < 15) {
            stage(it + 1, 0, c ^ 1);
            asm volatile("s_waitcnt vmcnt(2)");
        } else {
            asm volatile("s_waitcnt vmcnt(0)");
        }
        __builtin_amdgcn_s_barrier();
        bf16x8 bfr[4][2];
#pragma unroll
        for (int nt = 0; nt < 4; nt++)
#pragma unroll
            for (int h = 0; h < 2; h++)
                bfr[nt][h] = *(const bf16x8*)&Bs[c][(wn * 64 + nt * 16 + l15) * 64 +
                                                    ((((h << 2) | quad) ^ fs7) * 8)];
        {
            bf16x8 af[2][2];
#pragma unroll
            for (int m = 0; m < 2; m++)
#pragma unroll
                for (int h = 0; h < 2; h++)
                    af[m][h] = *(const bf16x8*)&As[c][(wm * 128 + m * 16 + l15) * 64 +
                                                      ((((h << 2) | quad) ^ fs7) * 8)];
            asm volatile("s_waitcnt lgkmcnt(0)");
            __builtin_amdgcn_sched_barrier(0);
            __builtin_amdgcn_s_setprio(1);
#pragma unroll
            for (int m = 0; m < 2; m++)
#pragma unroll
                for (int nt = 0; nt < 4; nt++)
#pragma unroll
                    for (int h = 0; h < 2; h++)
                        acc[m][nt] = __builtin_amdgcn_mfma_f32_16x16x32_bf16(
                            af[m][h], bfr[nt][h], acc[m][nt], 0, 0, 0);
            __builtin_amdgcn_s_setprio(0);
            __builtin_amdgcn_s_barrier();
        }
#pragma unroll
        for (int p = 1; p < 4; p++) {
            bf16x8 af[2][2];
#pragma unroll
            for (int m = 0; m < 2; m++)
#pragma unroll
                for (int h = 0; h < 2; h++)
                    af[m][h] = *(const bf16x8*)&As[c][(wm * 128 + (p * 2 + m) * 16 + l15) * 64 +
                                                      ((((h << 2) | quad) ^ fs7) * 8)];
            if (it < 15) stage(it + 1, p, c ^ 1);
            __builtin_amdgcn_s_barrier();
            asm volatile("s_waitcnt lgkmcnt(0)");
            __builtin_amdgcn_sched_barrier(0);
            __builtin_amdgcn_s_setprio(1);
#pragma unroll
            for (int m = 0; m < 2; m++)
#pragma unroll
                for (int nt = 0; nt < 4; nt++)
#pragma unroll
                    for (int h = 0; h < 2; h++)
                        acc[p * 2 + m][nt] = __builtin_amdgcn_mfma_f32_16x16x32_bf16(
                            af[m][h], bfr[nt][h], acc[p * 2 + m][nt], 0, 0, 0);
            __builtin_amdgcn_s_setprio(0);
            __builtin_amdgcn_s_barrier();
        }
    }

    if (sel == 2) {
        int b = m0 >> 11;
#pragma unroll
        for (int mt = 0; mt < 8; mt++) {
            int gr = m0 + wm * 128 + mt * 16 + quad * 4;
            int s = gr & 2047;
#pragma unroll
            for (int nt = 0; nt < 4; nt++) {
                int gcl = (n0 & 1023) + wn * 64 + nt * 16 + l15;   // = h*64+d
                float bb = bias[gcl];
                u16x4 pk;
#pragma unroll
                for (int r = 0; r < 4; r++) pk[r] = f2bf(acc[mt][nt][r] + bb);
                *(u16x4*)&Vt[(size_t)((b * 16 + (gcl >> 6)) * 64 + (gcl & 63)) * 2048 + s] = pk;
            }
        }
        return;
    }
    float qs = (sel == 0) ? 0.18033688011112f : 1.0f;  // log2(e)/sqrt(64) folded into Q
#pragma unroll
    for (int mt = 0; mt < 8; mt++) {
        int gr = m0 + wm * 128 + mt * 16 + quad * 4;
#pragma unroll
        for (int nt = 0; nt < 4; nt++) {
            int gc = n0 + wn * 64 + nt * 16 + l15;
            float bb = bias[gc & 1023];
#pragma unroll
            for (int r = 0; r < 4; r++)
                C[(size_t)(gr + r) * 3072 + gc] = f2bf((acc[mt][nt][r] + bb) * qs);
        }
    }
}

// ---------------- GEMM (proj): 128x128 tile, R2 single-buffer structure ----------------
template <bool OF32, bool VSPLIT>
__global__ __launch_bounds__(256) void gemm(
    const u16* __restrict__ Bt,
    const float* __restrict__ b0, const float* __restrict__ b1, const float* __restrict__ b2,
    const u16* __restrict__ A, void* __restrict__ Cptr, u16* __restrict__ Vt, int Ntot)
{
    __shared__ __align__(16) u16 As[128 * 32];
    __shared__ __align__(16) u16 Bs[128 * 32];
    int tid = threadIdx.x;
    int lane = tid & 63, l15 = lane & 15, quad = lane >> 4;
    int wid = tid >> 6, wm = wid >> 1, wn = wid & 1;
    int m0 = blockIdx.y * 128, n0 = blockIdx.x * 128;
    int sel = n0 >> 10;
    const float* bias = (sel == 0) ? b0 : ((sel == 1) ? b1 : b2);

    f32x4 acc[4][4];
#pragma unroll
    for (int i = 0; i < 4; i++)
#pragma unroll
        for (int j = 0; j < 4; j++) { f32x4 z = {0.f, 0.f, 0.f, 0.f}; acc[i][j] = z; }

    int rr = lane >> 2;
    int cc = (lane & 3) ^ ((rr >> 1) & 3);
    const u16* abase = A  + (size_t)m0 * 1024;
    const u16* bbase = Bt + (size_t)n0 * 1024;
    int fsw = (l15 >> 1) & 3;

    for (int k0 = 0; k0 < 1024; k0 += 32) {
#pragma unroll
        for (int inst = 0; inst < 2; inst++) {
            int r0 = wid * 32 + inst * 16;
            glds16(&abase[(size_t)(r0 + rr) * 1024 + k0 + cc * 8], &As[r0 * 32]);
            glds16(&bbase[(size_t)(r0 + rr) * 1024 + k0 + cc * 8], &Bs[r0 * 32]);
        }
        __syncthreads();
        bf16x8 af[4], bf[4];
#pragma unroll
        for (int mt = 0; mt < 4; mt++)
            af[mt] = *(const bf16x8*)&As[(wm * 64 + mt * 16 + l15) * 32 + ((quad ^ fsw) * 8)];
#pragma unroll
        for (int nt = 0; nt < 4; nt++)
            bf[nt] = *(const bf16x8*)&Bs[(wn * 64 + nt * 16 + l15) * 32 + ((quad ^ fsw) * 8)];
#pragma unroll
        for (int mt = 0; mt < 4; mt++)
#pragma unroll
            for (int nt = 0; nt < 4; nt++)
                acc[mt][nt] = __builtin_amdgcn_mfma_f32_16x16x32_bf16(af[mt], bf[nt], acc[mt][nt], 0, 0, 0);
        __syncthreads();
    }
    if (VSPLIT && sel == 2) {
        int b = m0 >> 11;
#pragma unroll
        for (int mt = 0; mt < 4; mt++) {
            int gr = m0 + wm * 64 + mt * 16 + quad * 4;
            int s = gr & 2047;
#pragma unroll
            for (int nt = 0; nt < 4; nt++) {
                int gcl = (n0 & 1023) + wn * 64 + nt * 16 + l15;
                float bb = bias[gcl];
                u16x4 pk;
#pragma unroll
                for (int r = 0; r < 4; r++) pk[r] = f2bf(acc[mt][nt][r] + bb);
                *(u16x4*)&Vt[(size_t)((b * 16 + (gcl >> 6)) * 64 + (gcl & 63)) * 2048 + s] = pk;
            }
        }
        return;
    }
    float qs = (VSPLIT && sel == 0) ? 0.18033688011112f : 1.0f;
#pragma unroll
    for (int mt = 0; mt < 4; mt++) {
        int gr = m0 + wm * 64 + mt * 16 + quad * 4;
#pragma unroll
        for (int nt = 0; nt < 4; nt++) {
            int gc = n0 + wn * 64 + nt * 16 + l15;
            float bb = bias[gc & 1023];
#pragma unroll
            for (int r = 0; r < 4; r++) {
                float v = (acc[mt][nt][r] + bb) * qs;
                if (OF32) ((float*)Cptr)[(size_t)(gr + r) * Ntot + gc] = v;
                else      ((u16*)Cptr)[(size_t)(gr + r) * Ntot + gc] = f2bf(v);
            }
        }
    }
}

// ---------------- MFMA flash attention, v4 ----------------
// Changes vs v3:
//  * 4-buffer LDS rotation, 2-tile-ahead prefetch, ONE barrier per iter.
//    Safety: stage at iter i writes buf (i+2)&3; its last readers were compute(i-2),
//    which completed before barrier B(i-1) <= B(i); the stage issues after B(i). The
//    post-PV barrier is gone -> waves drift into natural MFMA/VALU phase offsets.
//    vmcnt: 12 outstanding after stage -> vmcnt(8) = tile i landed (tail 4, 0).
//  * setprio(1) around both MFMA clusters (T5, attn-proven).
//  * V frag ds_reads issued before the exp chain (latency hides under exp).
//  * XCD-bijective block remap: all 16 qt-blocks of one (b,h) share an XCD
//    (lin&7 == g&7) -> K/V panel (512 KB) L2-resident per XCD (4 heads = 2 MB).
// Grid: 512 blocks x 256 thr (1-D), 2 blocks/CU, LDS 64 KB.
__global__ __launch_bounds__(256, 2) void attn(const u16* __restrict__ QKV, // [B*S][3072]
                                               const u16* __restrict__ Vt,  // [bh*64+d][2048]
                                               u16* __restrict__ O)         // [B*S][1024]
{
    __shared__ __align__(16) u16 Ks[4][64 * 64];  // [buf][j][d], XOR-swizzled chunks
    __shared__ __align__(16) u16 Vs[4][64 * 64];  // [buf][d][j], XOR-swizzled chunks
    const int S = 2048, DQ = 3072;
    int tid = threadIdx.x, wid = tid >> 6, lane = tid & 63;
    int l15 = lane & 15, quad = lane >> 4;
    // XCD-bijective remap: lin -> (qt, h, b) with lin%8 == (h+16b)%8
    int lin = blockIdx.x;
    int xcd = lin & 7;
    int rest = lin >> 3;            // 0..63
    int qt = rest & 15;
    int g = xcd + 8 * (rest >> 4);  // 0..31
    int h = g & 15, b = g >> 4;
    const u16* base = QKV + (size_t)b * S * DQ + h * 64;
    const u16* Kb = base + 1024;
    const u16* Vtb = Vt + (size_t)((b * 16 + h) * 64) * 2048;
    int q0 = qt * 128 + wid * 32;

    // Q fragments (B-operand of swapped QK^T): halves A (rows q0..+15) and B (q0+16..+31)
    bf16x8 qA0 = *(const bf16x8*)&base[(size_t)(q0 + l15) * DQ + quad * 8];
    bf16x8 qA1 = *(const bf16x8*)&base[(size_t)(q0 + l15) * DQ + 32 + quad * 8];
    bf16x8 qB0 = *(const bf16x8*)&base[(size_t)(q0 + 16 + l15) * DQ + quad * 8];
    bf16x8 qB1 = *(const bf16x8*)&base[(size_t)(q0 + 16 + l15) * DQ + 32 + quad * 8];

    f32x4 oA[4], oB[4];
#pragma unroll
    for (int i = 0; i < 4; i++) { f32x4 z = {0.f, 0.f, 0.f, 0.f}; oA[i] = z; oB[i] = z; }
    float psA = 0.f, psB = 0.f;   // per-lane partial row-sums for q=l15 (quad-partial in j)

    int rr = lane >> 3;            // row within 8-row glds inst
    int cc = (lane & 7) ^ rr;      // swizzled global chunk (row&7 == rr)
    int fs7 = l15 & 7;             // frag un-swizzle key

    auto stage = [&](int it, int bsel) {
        int kv0 = it << 6;
#pragma unroll
        for (int inst = 0; inst < 2; inst++) {
            int r0 = wid * 16 + inst * 8;
            glds16(&Kb[(size_t)(kv0 + r0 + rr) * DQ + cc * 8], &Ks[bsel][r0 * 64]);
            glds16(&Vtb[(size_t)(r0 + rr) * 2048 + kv0 + cc * 8], &Vs[bsel][r0 * 64]);
        }
    };

    stage(0, 0);                   // prologue: tiles 0,1 in flight (8 loads)
    stage(1, 1);
    for (int it = 0; it < 32; ++it) {
        int cb = it & 3;
        if (it < 30) {
            stage(it + 2, (it + 2) & 3);
            asm volatile("s_waitcnt vmcnt(8)");   // tile it landed (2 ahead in flight)
        } else if (it == 30) {
            asm volatile("s_waitcnt vmcnt(4)");
        } else {
            asm volatile("s_waitcnt vmcnt(0)");
        }
        __builtin_amdgcn_s_barrier();             // all waves' tile-it quarters landed

        const u16* Kc = &Ks[cb][0];
        const u16* Vc = &Vs[cb][0];
        // issue all K and V frag reads up front; V completes under the exp chain
        bf16x8 kfa[4], kfb[4], vfa[4], vfb[4];
#pragma unroll
        for (int t = 0; t < 4; t++) {
            kfa[t] = *(const bf16x8*)&Kc[(t * 16 + l15) * 64 + ((quad ^ fs7) * 8)];
            kfb[t] = *(const bf16x8*)&Kc[(t * 16 + l15) * 64 + (((quad + 4) ^ fs7) * 8)];
        }
#pragma unroll
        for (int dt = 0; dt < 4; dt++) {
            vfa[dt] = *(const bf16x8*)&Vc[(dt * 16 + l15) * 64 + ((quad ^ fs7) * 8)];
            vfb[dt] = *(const bf16x8*)&Vc[(dt * 16 + l15) * 64 + (((quad + 4) ^ fs7) * 8)];
        }

        // S^T = K Q^T : row(quad*4+r)=j_local, col(l15)=q ; K frags shared by both halves
        f32x4 sA[4], sB[4];
#pragma unroll
        for (int t = 0; t < 4; t++) { f32x4 z = {0.f, 0.f, 0.f, 0.f}; sA[t] = z; sB[t] = z; }
        __builtin_amdgcn_s_setprio(1);
#pragma unroll
        for (int t = 0; t < 4; t++) {
            sA[t] = __builtin_amdgcn_mfma_f32_16x16x32_bf16(kfa[t], qA0, sA[t], 0, 0, 0);
            sA[t] = __builtin_amdgcn_mfma_f32_16x16x32_bf16(kfb[t], qA1, sA[t], 0, 0, 0);
            sB[t] = __builtin_amdgcn_mfma_f32_16x16x32_bf16(kfa[t], qB0, sB[t], 0, 0, 0);
            sB[t] = __builtin_amdgcn_mfma_f32_16x16x32_bf16(kfb[t], qB1, sB[t], 0, 0, 0);
        }
        __builtin_amdgcn_s_setprio(0);

        // p = exp2(s) (scale pre-folded into Q); pack pairs into dwords; lane sums
        unsigned wA[4][2], wB[4][2];
#pragma unroll
        for (int t = 0; t < 4; t++) {
            float a0 = __builtin_amdgcn_exp2f(sA[t][0]);
            float a1 = __builtin_amdgcn_exp2f(sA[t][1]);
            float a2 = __builtin_amdgcn_exp2f(sA[t][2]);
            float a3 = __builtin_amdgcn_exp2f(sA[t][3]);
            psA += (a0 + a1) + (a2 + a3);
            asm("v_cvt_pk_bf16_f32 %0, %1, %2" : "=v"(wA[t][0]) : "v"(a0), "v"(a1));
            asm("v_cvt_pk_bf16_f32 %0, %1, %2" : "=v"(wA[t][1]) : "v"(a2), "v"(a3));
            float b0_ = __builtin_amdgcn_exp2f(sB[t][0]);
            float b1_ = __builtin_amdgcn_exp2f(sB[t][1]);
            float b2_ = __builtin_amdgcn_exp2f(sB[t][2]);
            float b3_ = __builtin_amdgcn_exp2f(sB[t][3]);
            psB += (b0_ + b1_) + (b2_ + b3_);
            asm("v_cvt_pk_bf16_f32 %0, %1, %2" : "=v"(wB[t][0]) : "v"(b0_), "v"(b1_));
            asm("v_cvt_pk_bf16_f32 %0, %1, %2" : "=v"(wB[t][1]) : "v"(b2_), "v"(b3_));
        }
        // in-register redistribution to PV A-fragments, per half
        unsigned a0 = wA[0][0], a2 = wA[1][0]; swap_half(a0, a2);
        unsigned a1 = wA[0][1], a3 = wA[1][1]; swap_half(a1, a3);
        unsigned c0 = wA[2][0], c2 = wA[3][0]; swap_half(c0, c2);
        unsigned c1 = wA[2][1], c3 = wA[3][1]; swap_half(c1, c3);
        u32x4 pdA0 = {a0, a1, a2, a3};
        u32x4 pdA1 = {c0, c1, c2, c3};
        bf16x8 pfA0 = *(bf16x8*)&pdA0;   // P_A[q=l15][j = quad*8 .. +7]
        bf16x8 pfA1 = *(bf16x8*)&pdA1;   // P_A[q=l15][j = 32+quad*8 .. +7]
        unsigned d0 = wB[0][0], d2 = wB[1][0]; swap_half(d0, d2);
        unsigned d1 = wB[0][1], d3 = wB[1][1]; swap_half(d1, d3);
        unsigned e0 = wB[2][0], e2 = wB[3][0]; swap_half(e0, e2);
        unsigned e1 = wB[2][1], e3 = wB[3][1]; swap_half(e1, e3);
        u32x4 pdB0 = {d0, d1, d2, d3};
        u32x4 pdB1 = {e0, e1, e2, e3};
        bf16x8 pfB0 = *(bf16x8*)&pdB0;
        bf16x8 pfB1 = *(bf16x8*)&pdB1;

        // O += P V : V frags shared by both halves
        __builtin_amdgcn_s_setprio(1);
#pragma unroll
        for (int dt = 0; dt < 4; dt++) {
            oA[dt] = __builtin_amdgcn_mfma_f32_16x16x32_bf16(pfA0, vfa[dt], oA[dt], 0, 0, 0);
            oA[dt] = __builtin_amdgcn_mfma_f32_16x16x32_bf16(pfA1, vfb[dt], oA[dt], 0, 0, 0);
            oB[dt] = __builtin_amdgcn_mfma_f32_16x16x32_bf16(pfB0, vfa[dt], oB[dt], 0, 0, 0);
            oB[dt] = __builtin_amdgcn_mfma_f32_16x16x32_bf16(pfB1, vfb[dt], oB[dt], 0, 0, 0);
        }
        __builtin_amdgcn_s_setprio(0);
        // no trailing barrier: next iter's stage targets buf (it+3)&3, whose readers
        // (compute it-1) all completed before this iter's pre-barrier.
    }

    // denominators: reduce quad-partials; lane sum is full row-sum for q=l15
    psA += __shfl_xor(psA, 16);
    psA += __shfl_xor(psA, 32);
    psB += __shfl_xor(psB, 16);
    psB += __shfl_xor(psB, 32);
#pragma unroll
    for (int r = 0; r < 4; r++) {
        float invA = 1.0f / __shfl(psA, quad * 4 + r);
        size_t rowA = (size_t)(b * S + q0 + quad * 4 + r);
#pragma unroll
        for (int dt = 0; dt < 4; dt++)
            O[rowA * 1024 + h * 64 + dt * 16 + l15] = f2bf(oA[dt][r] * invA);
        float invB = 1.0f / __shfl(psB, quad * 4 + r);
        size_t rowB = rowA + 16;
#pragma unroll
        for (int dt = 0; dt < 4; dt++)
            O[rowB * 1024 + h * 64 + dt * 16 + l15] = f2bf(oB[dt][r] * invB);
    }
}

extern "C" void kernel_launch(void* const* d_in, const int* in_sizes, int n_in,
                              void* d_out, int out_size, void* d_ws, size_t ws_size,
                              hipStream_t stream) {
    const float* x  = (const float*)d_in[0];
    const float* wq = (const float*)d_in[1];
    const float* bq = (const float*)d_in[2];
    const float* wk = (const float*)d_in[3];
    const float* bk = (const float*)d_in[4];
    const float* wv = (const float*)d_in[5];
    const float* bv = (const float*)d_in[6];
    const float* wo = (const float*)d_in[7];
    const float* bo = (const float*)d_in[8];
    float* out = (float*)d_out;

    u16* qkv  = (u16*)d_ws;
    u16* obuf = qkv  + (size_t)4096 * 3072;
    u16* vt   = obuf + (size_t)4096 * 1024;
    u16* wt   = vt   + (size_t)2048 * 2048;
    u16* xb   = wt   + (size_t)4 * 1024 * 1024;

    dim3 tb(256);
    prep<<<dim3(32, 32, 8), tb, 0, stream>>>(wq, wk, wv, wo, x, wt, xb);
    gemm256<<<dim3(12, 16), dim3(512), 0, stream>>>(wt, bq, bk, bv, xb, qkv, vt);
    attn<<<dim3(512), tb, 0, stream>>>(qkv, vt, obuf);
    gemm<true, false><<<dim3(8, 32), tb, 0, stream>>>(wt + (size_t)3 * 1024 * 1024,
                                                      bo, bo, bo, obuf, out, (u16*)nullptr, 1024);
}